// Round 12
// baseline (190.421 us; speedup 1.0000x reference)
//
#include <hip/hip_runtime.h>

#define FM_N   4
#define FM_C   256
#define FM_H   200
#define FM_W   336
#define CROP   14
#define NSAMP  (CROP * CROP)     // 196
#define HW     (FM_H * FM_W)     // 67200
#define HWB    (HW * 4)          // channel stride in bytes (268800)
#define CPB    16                // channels per (box, slice) item
#define NCG    (FM_C / CPB)      // 16 slices
#define NCGH   (NCG / 2)         // 8 slices per XCD-owned half
#define THREADS 256

typedef float f2 __attribute__((ext_vector_type(2)));
typedef struct { float x, y; } f2s;   // align-4 pair (fallback path)

// ---- per-box preamble (bit-identical op order, incl. the nh/spacing_w quirk) ----
__device__ __forceinline__ void box_preamble(const float* __restrict__ boxes, int m,
                                             float& x1n, float& y1n,
                                             float& step_x, float& step_y)
{
    const float bx1 = boxes[4 * m + 0];
    const float by1 = boxes[4 * m + 1];
    const float bx2 = boxes[4 * m + 2];
    const float by2 = boxes[4 * m + 3];
    const float spacing_w = __fdiv_rn(__fsub_rn(bx2, bx1), 14.0f);
    const float spacing_h = __fdiv_rn(__fsub_rn(by2, by1), 14.0f);
    const float nx0 = __fdiv_rn(__fsub_rn(__fadd_rn(bx1, __fdiv_rn(spacing_w, 2.0f)), 0.5f), 335.0f);
    const float ny0 = __fdiv_rn(__fsub_rn(__fadd_rn(by1, __fdiv_rn(spacing_h, 2.0f)), 0.5f), 199.0f);
    const float nw  = __fdiv_rn(__fmul_rn(spacing_w, 13.0f), 335.0f);
    const float nh  = __fdiv_rn(__fmul_rn(spacing_w, 13.0f), 199.0f);   // quirk: spacing_w
    y1n = ny0; x1n = nx0;
    const float y2n = __fadd_rn(ny0, nh);
    const float x2n = __fadd_rn(nx0, nw);
    step_y = __fdiv_rn(__fmul_rn(__fsub_rn(y2n, y1n), 199.0f), 13.0f);
    step_x = __fdiv_rn(__fmul_rn(__fsub_rn(x2n, x1n), 335.0f), 13.0f);
}

// ---------------- Kernel 1: bucket boxes by image (stable counting sort) -------------
__global__ __launch_bounds__(THREADS)
void bucket_kernel(const int* __restrict__ box_ind, int M,
                   int* __restrict__ perm, int* __restrict__ base)
{
    __shared__ int cnt[FM_N][THREADS];
    __shared__ int tot[FM_N], sbase[FM_N + 1];
    const int t = threadIdx.x;
    const int E = (M + THREADS - 1) / THREADS;

    int local[FM_N] = {0, 0, 0, 0};
    for (int e = 0; e < E; ++e) {
        const int idx = t * E + e;
        if (idx < M) local[box_ind[idx] & 3]++;
    }
    for (int b = 0; b < FM_N; ++b) cnt[b][t] = local[b];
    __syncthreads();
    if (t < FM_N) {
        int run = 0;
        for (int k = 0; k < THREADS; ++k) { const int c = cnt[t][k]; cnt[t][k] = run; run += c; }
        tot[t] = run;
    }
    __syncthreads();
    if (t == 0) {
        sbase[0] = 0;
        for (int b = 0; b < FM_N; ++b) sbase[b + 1] = sbase[b] + tot[b];
        for (int b = 0; b <= FM_N; ++b) base[b] = sbase[b];
    }
    __syncthreads();
    int off[FM_N];
    for (int b = 0; b < FM_N; ++b) off[b] = sbase[b] + cnt[b][t];
    for (int e = 0; e < E; ++e) {
        const int idx = t * E + e;
        if (idx < M) { const int v = box_ind[idx] & 3; perm[off[v]++] = idx; }
    }
}

// ---------------- Kernel 2: per-box interpolation tables (once per box) --------------
__global__ __launch_bounds__(THREADS)
void prep_kernel(const float* __restrict__ boxes, int M,
                 int4* __restrict__ ytab, int4* __restrict__ xtab)
{
    const int gid = blockIdx.x * THREADS + threadIdx.x;
    const int m = gid >> 5;
    const int r = gid & 31;
    if (m >= M || r >= 2 * CROP) return;

    float x1n, y1n, step_x, step_y;
    box_preamble(boxes, m, x1n, y1n, step_x, step_y);

    if (r < CROP) {
        const int i = r;
        const float in_y = __fadd_rn(__fmul_rn(y1n, 199.0f), __fmul_rn((float)i, step_y));
        const float my = ((in_y >= 0.0f) && (in_y <= 199.0f)) ? 1.0f : 0.0f;
        const float y0f = floorf(in_y);
        const float yf  = __fsub_rn(in_y, y0f);
        const int y0i = (int)fminf(fmaxf(y0f, 0.0f), 199.0f);
        const int y1i = (int)fminf(fmaxf(__fadd_rn(y0f, 1.0f), 0.0f), 199.0f);
        int4 v;
        v.x = __float_as_int(yf);
        v.y = __float_as_int(my);
        v.z = y0i * FM_W;
        v.w = y1i * FM_W;
        ytab[m * CROP + i] = v;
    } else {
        const int j = r - CROP;
        const float in_x = __fadd_rn(__fmul_rn(x1n, 335.0f), __fmul_rn((float)j, step_x));
        const float mx = ((in_x >= 0.0f) && (in_x <= 335.0f)) ? 1.0f : 0.0f;
        const float x0f = floorf(in_x);
        const float xf  = __fsub_rn(in_x, x0f);
        const int x0i = (int)fminf(fmaxf(x0f, 0.0f), 335.0f);
        const int x1i = (int)fminf(fmaxf(__fadd_rn(x0f, 1.0f), 0.0f), 335.0f);
        const int xa  = min(x0i, FM_W - 2);
        const int sb  = (x0i != xa ? 1 : 0) | (x1i != xa ? 2 : 0);
        int4 v;
        v.x = __float_as_int(xf);
        v.y = __float_as_int(mx);
        v.z = xa;
        v.w = sb;
        xtab[m * CROP + j] = v;
    }
}

// ---------------- Kernel 3: main gather+lerp, forced-MLP, 16 channels/item -----------
__global__ __launch_bounds__(THREADS)
void roialign_main(const float* __restrict__ fm,
                   const int4* __restrict__ ytab,
                   const int4* __restrict__ xtab,
                   const int* __restrict__ perm,
                   const int* __restrict__ base,
                   float* __restrict__ out)
{
    const int xcd = blockIdx.x & 7;       // linear_id % 8 -> XCD round-robin
    const int l   = blockIdx.x >> 3;
    const int I   = xcd >> 1;             // owned image
    const int h   = xcd & 1;              // owned channel half
    const int b0  = base[I];
    const int nI  = base[I + 1] - b0;
    const int perXcdX = gridDim.x >> 3;
    const int slots   = perXcdX * gridDim.y;
    const int w0      = blockIdx.y * perXcdX + l;

    const int t = threadIdx.x;
    const int i = t >> 4;
    const int j = t & 15;
    const bool act = (i < CROP) && (j < CROP);

    const int work = nI * NCGH;
    for (int w = w0; w < work; w += slots) {
        const int cgh = w / nI;           // slice-major: slice stays L2-resident
        const int mi  = w - cgh * nI;
        const int m   = perm[b0 + mi];
        const int cg  = h * NCGH + cgh;

        if (act) {
            const int4 yv = ytab[m * CROP + i];
            const int4 xv = xtab[m * CROP + j];
            const float yf = __int_as_float(yv.x);
            const float my = __int_as_float(yv.y);
            const float xf = __int_as_float(xv.x);
            const float mx = __int_as_float(xv.y);
            const float mk = __fmul_rn(my, mx);
            const bool sel0 = (xv.w & 1) != 0;
            const bool sel1 = (xv.w & 2) != 0;

            const float* __restrict__ pc =
                fm + ((size_t)I * FM_C + (size_t)cg * CPB) * HW;
            const unsigned long long sb64 = (unsigned long long)pc;   // uniform -> SGPR pair
            const unsigned int offA = (unsigned int)((yv.z + xv.z) * 4);  // top-row byte off
            const unsigned int offB = (unsigned int)((yv.w + xv.z) * 4);  // bottom-row byte off

            // ---- issue ALL 32 pair-loads back-to-back (forced MLP=32) ----
            f2 a0,a1,a2,a3,a4,a5,a6,a7,a8,a9,a10,a11,a12,a13,a14,a15;
            f2 c0,c1,c2,c3,c4,c5,c6,c7,c8,c9,c10,c11,c12,c13,c14,c15;
#define GL(dst, off) \
    asm volatile("global_load_dwordx2 %0, %1, %2" : "=v"(dst) : "v"(off), "s"(sb64))
            GL(a0,  offA +  0u * HWB);  GL(c0,  offB +  0u * HWB);
            GL(a1,  offA +  1u * HWB);  GL(c1,  offB +  1u * HWB);
            GL(a2,  offA +  2u * HWB);  GL(c2,  offB +  2u * HWB);
            GL(a3,  offA +  3u * HWB);  GL(c3,  offB +  3u * HWB);
            GL(a4,  offA +  4u * HWB);  GL(c4,  offB +  4u * HWB);
            GL(a5,  offA +  5u * HWB);  GL(c5,  offB +  5u * HWB);
            GL(a6,  offA +  6u * HWB);  GL(c6,  offB +  6u * HWB);
            GL(a7,  offA +  7u * HWB);  GL(c7,  offB +  7u * HWB);
            GL(a8,  offA +  8u * HWB);  GL(c8,  offB +  8u * HWB);
            GL(a9,  offA +  9u * HWB);  GL(c9,  offB +  9u * HWB);
            GL(a10, offA + 10u * HWB);  GL(c10, offB + 10u * HWB);
            GL(a11, offA + 11u * HWB);  GL(c11, offB + 11u * HWB);
            GL(a12, offA + 12u * HWB);  GL(c12, offB + 12u * HWB);
            GL(a13, offA + 13u * HWB);  GL(c13, offB + 13u * HWB);
            GL(a14, offA + 14u * HWB);  GL(c14, offB + 14u * HWB);
            GL(a15, offA + 15u * HWB);  GL(c15, offB + 15u * HWB);
#undef GL
            asm volatile("s_waitcnt vmcnt(0)" ::: "memory");
            __builtin_amdgcn_sched_barrier(0);   // rule #18: keep consumers below waitcnt

            float* __restrict__ op =
                out + ((size_t)m * FM_C + (size_t)cg * CPB) * NSAMP + i * CROP + j;
#define LERP(va, vb, c)                                                            \
    {                                                                              \
        const float tl = sel0 ? va.y : va.x;                                       \
        const float tr = sel1 ? va.y : va.x;                                       \
        const float bl = sel0 ? vb.y : vb.x;                                       \
        const float br = sel1 ? vb.y : vb.x;                                       \
        const float top = __fadd_rn(tl, __fmul_rn(__fsub_rn(tr, tl), xf));         \
        const float bot = __fadd_rn(bl, __fmul_rn(__fsub_rn(br, bl), xf));         \
        const float o   = __fadd_rn(top, __fmul_rn(__fsub_rn(bot, top), yf));      \
        op[c * NSAMP] = __fmul_rn(o, mk);                                          \
    }
            LERP(a0,  c0,  0)  LERP(a1,  c1,  1)  LERP(a2,  c2,  2)  LERP(a3,  c3,  3)
            LERP(a4,  c4,  4)  LERP(a5,  c5,  5)  LERP(a6,  c6,  6)  LERP(a7,  c7,  7)
            LERP(a8,  c8,  8)  LERP(a9,  c9,  9)  LERP(a10, c10, 10) LERP(a11, c11, 11)
            LERP(a12, c12, 12) LERP(a13, c13, 13) LERP(a14, c14, 14) LERP(a15, c15, 15)
#undef LERP
        }
    }
}

// ---------------- Fallback (fused kernel) if ws is too small -------------------------
__global__ __launch_bounds__(THREADS)
void roialign_fb(const float* __restrict__ fm,
                 const float* __restrict__ boxes,
                 const int* __restrict__ perm,
                 const int* __restrict__ base,
                 float* __restrict__ out)
{
    const int xcd = blockIdx.x & 7;
    const int l   = blockIdx.x >> 3;
    const int I   = xcd >> 1;
    const int h   = xcd & 1;
    const int b0  = base[I];
    const int nI  = base[I + 1] - b0;
    const int perXcdX = gridDim.x >> 3;
    const int slots   = perXcdX * gridDim.y;
    const int w0      = blockIdx.y * perXcdX + l;

    const int t = threadIdx.x;
    const int i = t >> 4;
    const int j = t & 15;
    const bool act = (i < CROP) && (j < CROP);

    const int work = nI * NCGH;
    for (int w = w0; w < work; w += slots) {
        const int cgh = w / nI;
        const int mi  = w - cgh * nI;
        const int m   = perm[b0 + mi];
        const int cg  = h * NCGH + cgh;
        if (act) {
            float x1n, y1n, step_x, step_y;
            box_preamble(boxes, m, x1n, y1n, step_x, step_y);
            const float in_y = __fadd_rn(__fmul_rn(y1n, 199.0f), __fmul_rn((float)i, step_y));
            const float in_x = __fadd_rn(__fmul_rn(x1n, 335.0f), __fmul_rn((float)j, step_x));
            const bool valid = (in_y >= 0.0f) && (in_y <= 199.0f) &&
                               (in_x >= 0.0f) && (in_x <= 335.0f);
            const float mk = valid ? 1.0f : 0.0f;
            const float y0f = floorf(in_y);
            const float x0f = floorf(in_x);
            const float yf  = __fsub_rn(in_y, y0f);
            const float xf  = __fsub_rn(in_x, x0f);
            const int y0i = (int)fminf(fmaxf(y0f, 0.0f), 199.0f);
            const int y1i = (int)fminf(fmaxf(__fadd_rn(y0f, 1.0f), 0.0f), 199.0f);
            const int x0i = (int)fminf(fmaxf(x0f, 0.0f), 335.0f);
            const int x1i = (int)fminf(fmaxf(__fadd_rn(x0f, 1.0f), 0.0f), 335.0f);
            const int  xa   = min(x0i, FM_W - 2);
            const bool sel0 = (x0i != xa);
            const bool sel1 = (x1i != xa);
            const int  oya  = y0i * FM_W + xa;
            const int  oyb  = y1i * FM_W + xa;
            const float* __restrict__ pc = fm + ((size_t)I * FM_C + (size_t)cg * CPB) * HW;
            float* __restrict__ op = out + ((size_t)m * FM_C + (size_t)cg * CPB) * NSAMP + i * CROP + j;
            #pragma unroll
            for (int c = 0; c < CPB; ++c) {
                const f2s va = *(const f2s*)(pc + oya);
                const f2s vb = *(const f2s*)(pc + oyb);
                pc += HW;
                const float tl = sel0 ? va.y : va.x;
                const float tr = sel1 ? va.y : va.x;
                const float bl = sel0 ? vb.y : vb.x;
                const float br = sel1 ? vb.y : vb.x;
                const float top = __fadd_rn(tl, __fmul_rn(__fsub_rn(tr, tl), xf));
                const float bot = __fadd_rn(bl, __fmul_rn(__fsub_rn(br, bl), xf));
                const float o   = __fadd_rn(top, __fmul_rn(__fsub_rn(bot, top), yf));
                *op = __fmul_rn(o, mk);
                op += NSAMP;
            }
        }
    }
}

extern "C" void kernel_launch(void* const* d_in, const int* in_sizes, int n_in,
                              void* d_out, int out_size, void* d_ws, size_t ws_size,
                              hipStream_t stream) {
    const float* fm      = (const float*)d_in[0];
    const float* boxes   = (const float*)d_in[1];
    const int*   box_ind = (const int*)d_in[2];
    float*       out     = (float*)d_out;

    const int M = in_sizes[2];            // 1024 boxes

    int* perm = (int*)d_ws;               // [M]
    int* base = perm + M;                 // [5]
    const size_t tab_off = (((size_t)(M + 5) * 4) + 15) & ~(size_t)15;
    int4* ytab = (int4*)((char*)d_ws + tab_off);        // [M*14]
    int4* xtab = ytab + (size_t)M * CROP;               // [M*14]
    const size_t needed = tab_off + 2 * (size_t)M * CROP * sizeof(int4);

    bucket_kernel<<<1, THREADS, 0, stream>>>(box_ind, M, perm, base);

    const int gx = 2048;                  // %8==0; 256 x-slots per XCD
    dim3 grid(gx, NCG);                   // slots/XCD = 256*16 = 4096 >= worst work
    if (ws_size >= needed) {
        prep_kernel<<<(M * 32 + THREADS - 1) / THREADS, THREADS, 0, stream>>>(boxes, M, ytab, xtab);
        roialign_main<<<grid, THREADS, 0, stream>>>(fm, ytab, xtab, perm, base, out);
    } else {
        roialign_fb<<<grid, THREADS, 0, stream>>>(fm, boxes, perm, base, out);
    }
}

// Round 13
// 182.584 us; speedup vs baseline: 1.0429x; 1.0429x over previous
//
#include <hip/hip_runtime.h>

#define FM_N   4
#define FM_C   256
#define FM_H   200
#define FM_W   336
#define CROP   14
#define NSAMP  (CROP * CROP)     // 196
#define HW     (FM_H * FM_W)     // 67200
#define HWB    (HW * 4)          // channel stride in bytes (268800)
#define CPB    8                 // channels per (box, slice) item — L2-slice sweet spot
#define NCG    (FM_C / CPB)      // 32 slices
#define NCGH   (NCG / 2)         // 16 slices per XCD-owned half
#define THREADS 256

typedef float f2 __attribute__((ext_vector_type(2)));
// 8-byte pair with natural 4-byte alignment (fallback path)
typedef struct { float x, y; } f2s;

// ---- per-box preamble (bit-identical op order, incl. the nh/spacing_w quirk) ----
__device__ __forceinline__ void box_preamble(const float* __restrict__ boxes, int m,
                                             float& x1n, float& y1n,
                                             float& step_x, float& step_y)
{
    const float bx1 = boxes[4 * m + 0];
    const float by1 = boxes[4 * m + 1];
    const float bx2 = boxes[4 * m + 2];
    const float by2 = boxes[4 * m + 3];
    const float spacing_w = __fdiv_rn(__fsub_rn(bx2, bx1), 14.0f);
    const float spacing_h = __fdiv_rn(__fsub_rn(by2, by1), 14.0f);
    const float nx0 = __fdiv_rn(__fsub_rn(__fadd_rn(bx1, __fdiv_rn(spacing_w, 2.0f)), 0.5f), 335.0f);
    const float ny0 = __fdiv_rn(__fsub_rn(__fadd_rn(by1, __fdiv_rn(spacing_h, 2.0f)), 0.5f), 199.0f);
    const float nw  = __fdiv_rn(__fmul_rn(spacing_w, 13.0f), 335.0f);
    const float nh  = __fdiv_rn(__fmul_rn(spacing_w, 13.0f), 199.0f);   // quirk: spacing_w
    y1n = ny0; x1n = nx0;
    const float y2n = __fadd_rn(ny0, nh);
    const float x2n = __fadd_rn(nx0, nw);
    step_y = __fdiv_rn(__fmul_rn(__fsub_rn(y2n, y1n), 199.0f), 13.0f);
    step_x = __fdiv_rn(__fmul_rn(__fsub_rn(x2n, x1n), 335.0f), 13.0f);
}

// ---------------- Kernel 1: bucket boxes by image (stable counting sort) -------------
__global__ __launch_bounds__(THREADS)
void bucket_kernel(const int* __restrict__ box_ind, int M,
                   int* __restrict__ perm, int* __restrict__ base)
{
    __shared__ int cnt[FM_N][THREADS];
    __shared__ int tot[FM_N], sbase[FM_N + 1];
    const int t = threadIdx.x;
    const int E = (M + THREADS - 1) / THREADS;

    int local[FM_N] = {0, 0, 0, 0};
    for (int e = 0; e < E; ++e) {
        const int idx = t * E + e;
        if (idx < M) local[box_ind[idx] & 3]++;
    }
    for (int b = 0; b < FM_N; ++b) cnt[b][t] = local[b];
    __syncthreads();
    if (t < FM_N) {
        int run = 0;
        for (int k = 0; k < THREADS; ++k) { const int c = cnt[t][k]; cnt[t][k] = run; run += c; }
        tot[t] = run;
    }
    __syncthreads();
    if (t == 0) {
        sbase[0] = 0;
        for (int b = 0; b < FM_N; ++b) sbase[b + 1] = sbase[b] + tot[b];
        for (int b = 0; b <= FM_N; ++b) base[b] = sbase[b];
    }
    __syncthreads();
    int off[FM_N];
    for (int b = 0; b < FM_N; ++b) off[b] = sbase[b] + cnt[b][t];
    for (int e = 0; e < E; ++e) {
        const int idx = t * E + e;
        if (idx < M) { const int v = box_ind[idx] & 3; perm[off[v]++] = idx; }
    }
}

// ---------------- Kernel 2: per-box interpolation tables (once per box) --------------
__global__ __launch_bounds__(THREADS)
void prep_kernel(const float* __restrict__ boxes, int M,
                 int4* __restrict__ ytab, int4* __restrict__ xtab)
{
    const int gid = blockIdx.x * THREADS + threadIdx.x;
    const int m = gid >> 5;
    const int r = gid & 31;
    if (m >= M || r >= 2 * CROP) return;

    float x1n, y1n, step_x, step_y;
    box_preamble(boxes, m, x1n, y1n, step_x, step_y);

    if (r < CROP) {
        const int i = r;
        const float in_y = __fadd_rn(__fmul_rn(y1n, 199.0f), __fmul_rn((float)i, step_y));
        const float my = ((in_y >= 0.0f) && (in_y <= 199.0f)) ? 1.0f : 0.0f;
        const float y0f = floorf(in_y);
        const float yf  = __fsub_rn(in_y, y0f);
        const int y0i = (int)fminf(fmaxf(y0f, 0.0f), 199.0f);
        const int y1i = (int)fminf(fmaxf(__fadd_rn(y0f, 1.0f), 0.0f), 199.0f);
        int4 v;
        v.x = __float_as_int(yf);
        v.y = __float_as_int(my);
        v.z = y0i * FM_W;
        v.w = y1i * FM_W;
        ytab[m * CROP + i] = v;
    } else {
        const int j = r - CROP;
        const float in_x = __fadd_rn(__fmul_rn(x1n, 335.0f), __fmul_rn((float)j, step_x));
        const float mx = ((in_x >= 0.0f) && (in_x <= 335.0f)) ? 1.0f : 0.0f;
        const float x0f = floorf(in_x);
        const float xf  = __fsub_rn(in_x, x0f);
        const int x0i = (int)fminf(fmaxf(x0f, 0.0f), 335.0f);
        const int x1i = (int)fminf(fmaxf(__fadd_rn(x0f, 1.0f), 0.0f), 335.0f);
        const int xa  = min(x0i, FM_W - 2);
        const int sb  = (x0i != xa ? 1 : 0) | (x1i != xa ? 2 : 0);
        int4 v;
        v.x = __float_as_int(xf);
        v.y = __float_as_int(mx);
        v.z = xa;
        v.w = sb;
        xtab[m * CROP + j] = v;
    }
}

// ---------------- Kernel 3: main gather+lerp, forced-MLP inline-asm loads ------------
__global__ __launch_bounds__(THREADS)
void roialign_main(const float* __restrict__ fm,
                   const int4* __restrict__ ytab,
                   const int4* __restrict__ xtab,
                   const int* __restrict__ perm,
                   const int* __restrict__ base,
                   float* __restrict__ out)
{
    const int xcd = blockIdx.x & 7;       // linear_id % 8 -> XCD round-robin
    const int l   = blockIdx.x >> 3;
    const int I   = xcd >> 1;             // owned image
    const int h   = xcd & 1;              // owned channel half
    const int b0  = base[I];
    const int nI  = base[I + 1] - b0;
    const int perXcdX = gridDim.x >> 3;
    const int slots   = perXcdX * gridDim.y;
    const int w0      = blockIdx.y * perXcdX + l;

    const int t = threadIdx.x;
    const int i = t >> 4;
    const int j = t & 15;
    const bool act = (i < CROP) && (j < CROP);

    const int work = nI * NCGH;
    for (int w = w0; w < work; w += slots) {
        const int cgh = w / nI;           // slice-major: slice stays L2-resident
        const int mi  = w - cgh * nI;
        const int m   = perm[b0 + mi];
        const int cg  = h * NCGH + cgh;

        if (act) {
            const int4 yv = ytab[m * CROP + i];
            const int4 xv = xtab[m * CROP + j];
            const float yf = __int_as_float(yv.x);
            const float my = __int_as_float(yv.y);
            const float xf = __int_as_float(xv.x);
            const float mx = __int_as_float(xv.y);
            const float mk = __fmul_rn(my, mx);
            const bool sel0 = (xv.w & 1) != 0;
            const bool sel1 = (xv.w & 2) != 0;

            const float* __restrict__ pc =
                fm + ((size_t)I * FM_C + (size_t)cg * CPB) * HW;
            const unsigned long long sb64 = (unsigned long long)pc;   // uniform -> SGPR pair
            const unsigned int offA = (unsigned int)((yv.z + xv.z) * 4);  // top-row byte off
            const unsigned int offB = (unsigned int)((yv.w + xv.z) * 4);  // bottom-row byte off

            // ---- issue ALL 16 pair-loads back-to-back (forced MLP=16) ----
            f2 a0, a1, a2, a3, a4, a5, a6, a7;
            f2 b0v, b1v, b2v, b3v, b4v, b5v, b6v, b7v;
#define GL(dst, off) \
    asm volatile("global_load_dwordx2 %0, %1, %2" : "=v"(dst) : "v"(off), "s"(sb64))
            GL(a0, offA + 0u * HWB);  GL(b0v, offB + 0u * HWB);
            GL(a1, offA + 1u * HWB);  GL(b1v, offB + 1u * HWB);
            GL(a2, offA + 2u * HWB);  GL(b2v, offB + 2u * HWB);
            GL(a3, offA + 3u * HWB);  GL(b3v, offB + 3u * HWB);
            GL(a4, offA + 4u * HWB);  GL(b4v, offB + 4u * HWB);
            GL(a5, offA + 5u * HWB);  GL(b5v, offB + 5u * HWB);
            GL(a6, offA + 6u * HWB);  GL(b6v, offB + 6u * HWB);
            GL(a7, offA + 7u * HWB);  GL(b7v, offB + 7u * HWB);
#undef GL
            asm volatile("s_waitcnt vmcnt(0)" ::: "memory");
            __builtin_amdgcn_sched_barrier(0);   // rule #18: keep consumers below waitcnt

            float* __restrict__ op =
                out + ((size_t)m * FM_C + (size_t)cg * CPB) * NSAMP + i * CROP + j;
#define LERP(va, vb, c)                                                            \
    {                                                                              \
        const float tl = sel0 ? va.y : va.x;                                       \
        const float tr = sel1 ? va.y : va.x;                                       \
        const float bl = sel0 ? vb.y : vb.x;                                       \
        const float br = sel1 ? vb.y : vb.x;                                       \
        const float top = __fadd_rn(tl, __fmul_rn(__fsub_rn(tr, tl), xf));         \
        const float bot = __fadd_rn(bl, __fmul_rn(__fsub_rn(br, bl), xf));         \
        const float o   = __fadd_rn(top, __fmul_rn(__fsub_rn(bot, top), yf));      \
        op[c * NSAMP] = __fmul_rn(o, mk);                                          \
    }
            LERP(a0, b0v, 0) LERP(a1, b1v, 1) LERP(a2, b2v, 2) LERP(a3, b3v, 3)
            LERP(a4, b4v, 4) LERP(a5, b5v, 5) LERP(a6, b6v, 6) LERP(a7, b7v, 7)
#undef LERP
        }
    }
}

// ---------------- Fallback (R8-proven fused kernel) if ws is too small ---------------
__global__ __launch_bounds__(THREADS)
void roialign_fb(const float* __restrict__ fm,
                 const float* __restrict__ boxes,
                 const int* __restrict__ perm,
                 const int* __restrict__ base,
                 float* __restrict__ out)
{
    const int xcd = blockIdx.x & 7;
    const int l   = blockIdx.x >> 3;
    const int I   = xcd >> 1;
    const int h   = xcd & 1;
    const int b0  = base[I];
    const int nI  = base[I + 1] - b0;
    const int perXcdX = gridDim.x >> 3;
    const int slots   = perXcdX * gridDim.y;
    const int w0      = blockIdx.y * perXcdX + l;

    const int t = threadIdx.x;
    const int i = t >> 4;
    const int j = t & 15;
    const bool act = (i < CROP) && (j < CROP);

    const int work = nI * NCGH;
    for (int w = w0; w < work; w += slots) {
        const int cgh = w / nI;
        const int mi  = w - cgh * nI;
        const int m   = perm[b0 + mi];
        const int cg  = h * NCGH + cgh;
        if (act) {
            float x1n, y1n, step_x, step_y;
            box_preamble(boxes, m, x1n, y1n, step_x, step_y);
            const float in_y = __fadd_rn(__fmul_rn(y1n, 199.0f), __fmul_rn((float)i, step_y));
            const float in_x = __fadd_rn(__fmul_rn(x1n, 335.0f), __fmul_rn((float)j, step_x));
            const bool valid = (in_y >= 0.0f) && (in_y <= 199.0f) &&
                               (in_x >= 0.0f) && (in_x <= 335.0f);
            const float mk = valid ? 1.0f : 0.0f;
            const float y0f = floorf(in_y);
            const float x0f = floorf(in_x);
            const float yf  = __fsub_rn(in_y, y0f);
            const float xf  = __fsub_rn(in_x, x0f);
            const int y0i = (int)fminf(fmaxf(y0f, 0.0f), 199.0f);
            const int y1i = (int)fminf(fmaxf(__fadd_rn(y0f, 1.0f), 0.0f), 199.0f);
            const int x0i = (int)fminf(fmaxf(x0f, 0.0f), 335.0f);
            const int x1i = (int)fminf(fmaxf(__fadd_rn(x0f, 1.0f), 0.0f), 335.0f);
            const int  xa   = min(x0i, FM_W - 2);
            const bool sel0 = (x0i != xa);
            const bool sel1 = (x1i != xa);
            const int  oya  = y0i * FM_W + xa;
            const int  oyb  = y1i * FM_W + xa;
            const float* __restrict__ pc = fm + ((size_t)I * FM_C + (size_t)cg * CPB) * HW;
            float* __restrict__ op = out + ((size_t)m * FM_C + (size_t)cg * CPB) * NSAMP + i * CROP + j;
            #pragma unroll
            for (int c = 0; c < CPB; ++c) {
                const f2s va = *(const f2s*)(pc + oya);
                const f2s vb = *(const f2s*)(pc + oyb);
                pc += HW;
                const float tl = sel0 ? va.y : va.x;
                const float tr = sel1 ? va.y : va.x;
                const float bl = sel0 ? vb.y : vb.x;
                const float br = sel1 ? vb.y : vb.x;
                const float top = __fadd_rn(tl, __fmul_rn(__fsub_rn(tr, tl), xf));
                const float bot = __fadd_rn(bl, __fmul_rn(__fsub_rn(br, bl), xf));
                const float o   = __fadd_rn(top, __fmul_rn(__fsub_rn(bot, top), yf));
                *op = __fmul_rn(o, mk);
                op += NSAMP;
            }
        }
    }
}

extern "C" void kernel_launch(void* const* d_in, const int* in_sizes, int n_in,
                              void* d_out, int out_size, void* d_ws, size_t ws_size,
                              hipStream_t stream) {
    const float* fm      = (const float*)d_in[0];
    const float* boxes   = (const float*)d_in[1];
    const int*   box_ind = (const int*)d_in[2];
    float*       out     = (float*)d_out;

    const int M = in_sizes[2];            // 1024 boxes

    int* perm = (int*)d_ws;               // [M]
    int* base = perm + M;                 // [5]
    const size_t tab_off = (((size_t)(M + 5) * 4) + 15) & ~(size_t)15;
    int4* ytab = (int4*)((char*)d_ws + tab_off);        // [M*14]
    int4* xtab = ytab + (size_t)M * CROP;               // [M*14]
    const size_t needed = tab_off + 2 * (size_t)M * CROP * sizeof(int4);

    bucket_kernel<<<1, THREADS, 0, stream>>>(box_ind, M, perm, base);

    const int gx = 1280;                  // %8==0; 160 x-slots per XCD
    dim3 grid(gx, NCG);                   // slots/XCD = 5120 >= worst-case work
    if (ws_size >= needed) {
        prep_kernel<<<(M * 32 + THREADS - 1) / THREADS, THREADS, 0, stream>>>(boxes, M, ytab, xtab);
        roialign_main<<<grid, THREADS, 0, stream>>>(fm, ytab, xtab, perm, base, out);
    } else {
        roialign_fb<<<grid, THREADS, 0, stream>>>(fm, boxes, perm, base, out);
    }
}